// Round 20
// baseline (238.616 us; speedup 1.0000x reference)
//
#include <hip/hip_runtime.h>
#include <hip/hip_bf16.h>
#include <stdint.h>

#define T_TOK 2048
#define H_DIM 2048
#define I_DIM 1408
#define NEXP  8
#define NPOS  4096   // T_TOK * top_k
#define NPAD  5120   // max padded rows: 4096 + 8*128
#define MAXT  40     // NPAD / 128

typedef short short8 __attribute__((ext_vector_type(8)));
typedef float f32x4  __attribute__((ext_vector_type(4)));

// f32 -> bf16 RNE (finite inputs only)
__device__ __forceinline__ short f2bf(float f) {
  union { float f; uint32_t u; } v; v.f = f;
  uint32_t r = (v.u + 0x7FFFu + ((v.u >> 16) & 1u)) >> 16;
  return (short)r;
}
__device__ __forceinline__ float bf2f(short s) {
  union { uint32_t u; float f; } v; v.u = ((uint32_t)(uint16_t)s) << 16;
  return v.f;
}

// 8x f32 -> bf16 via packed HW cvt (v_cvt_pk_bf16_f32), RNE — matches f2bf
__device__ __forceinline__ short8 cvt8(f32x4 a, f32x4 b) {
  __hip_bfloat162 h0 = __float22bfloat162_rn(float2{a[0], a[1]});
  __hip_bfloat162 h1 = __float22bfloat162_rn(float2{a[2], a[3]});
  __hip_bfloat162 h2 = __float22bfloat162_rn(float2{b[0], b[1]});
  __hip_bfloat162 h3 = __float22bfloat162_rn(float2{b[2], b[3]});
  short2 s0, s1, s2, s3;
  __builtin_memcpy(&s0, &h0, 4); __builtin_memcpy(&s1, &h1, 4);
  __builtin_memcpy(&s2, &h2, 4); __builtin_memcpy(&s3, &h3, 4);
  short8 r;
  r[0] = s0.x; r[1] = s0.y; r[2] = s1.x; r[3] = s1.y;
  r[4] = s2.x; r[5] = s2.y; r[6] = s3.x; r[7] = s3.y;
  return r;
}

// async global->LDS, 16B per lane. LDS dest = wave-uniform base + lane*16.
__device__ __forceinline__ void load_lds16(const void* g, void* l) {
  __builtin_amdgcn_global_load_lds((const __attribute__((address_space(1))) uint32_t*)g,
                                   (__attribute__((address_space(3))) uint32_t*)l,
                                   16, 0, 0);
}

// ---------------------------------------------------------------------------
// Kernel 1: routing. Single block, 1024 threads. Top-2 of 8 logits,
// 128-PADDED per-expert grouping. Pad slots: token 0, weight 0 (self-masking).
// Emits inverse map inv[2t], inv[2t+1] = the two pos slots of token t.
// ---------------------------------------------------------------------------
__global__ void k_routing(const float* __restrict__ logits,
                          int* __restrict__ pos_token,
                          float* __restrict__ pos_w,
                          int* __restrict__ eoff,
                          int* __restrict__ inv) {
  __shared__ int   s_ids[T_TOK];
  __shared__ float s_w0[T_TOK];
  __shared__ float s_w1[T_TOK];
  __shared__ int s_cnt[NEXP], s_cur[NEXP], s_off[NEXP + 1];
  const int tid = threadIdx.x;
  if (tid < NEXP) { s_cnt[tid] = 0; s_cur[tid] = 0; }
  for (int p = tid; p < NPAD; p += blockDim.x) { pos_token[p] = 0; pos_w[p] = 0.f; }
  __syncthreads();

  for (int t = tid; t < T_TOK; t += blockDim.x) {
    float l[NEXP];
#pragma unroll
    for (int e = 0; e < NEXP; ++e) l[e] = logits[t * NEXP + e];
    int b0 = 0; float v0 = l[0];
#pragma unroll
    for (int e = 1; e < NEXP; ++e) if (l[e] > v0) { v0 = l[e]; b0 = e; }
    int b1 = -1; float v1 = -1e30f;
#pragma unroll
    for (int e = 0; e < NEXP; ++e) if (e != b0 && l[e] > v1) { v1 = l[e]; b1 = e; }
    float t1 = __expf(v1 - v0);
    float w0 = 1.f / (1.f + t1);
    float w1 = 1.f - w0;
    s_ids[t] = b0 | (b1 << 8);
    s_w0[t] = w0; s_w1[t] = w1;
    atomicAdd(&s_cnt[b0], 1);
    atomicAdd(&s_cnt[b1], 1);
  }
  __syncthreads();
  if (tid == 0) {
    int acc = 0;
    for (int e = 0; e < NEXP; ++e) {
      s_off[e] = acc;
      acc += (s_cnt[e] + 127) & ~127;   // 128-padded
    }
    s_off[NEXP] = acc;
    for (int e = 0; e <= NEXP; ++e) eoff[e] = s_off[e];
  }
  __syncthreads();
  for (int t = tid; t < T_TOK; t += blockDim.x) {
    int ids = s_ids[t];
    int e0 = ids & 255, e1 = ids >> 8;
    int p0 = s_off[e0] + atomicAdd(&s_cur[e0], 1);
    pos_token[p0] = t; pos_w[p0] = s_w0[t];
    int p1 = s_off[e1] + atomicAdd(&s_cur[e1], 1);
    pos_token[p1] = t; pos_w[p1] = s_w1[t];
    inv[2 * t] = p0; inv[2 * t + 1] = p1;
  }
}

// ---------------------------------------------------------------------------
// Kernel 2: gather+cast x rows into grouped (padded) order, bf16.
// ---------------------------------------------------------------------------
__global__ void k_gather(const float* __restrict__ x,
                         const int* __restrict__ pos_token,
                         short* __restrict__ xg) {
  const int p = blockIdx.x;
  const int tid = threadIdx.x;
  const int tok = pos_token[p];
  const f32x4* src = (const f32x4*)(x + (size_t)tok * H_DIM);
  f32x4 a = src[tid * 2];
  f32x4 b = src[tid * 2 + 1];
  ((short8*)(xg + (size_t)p * H_DIM))[tid] = cvt8(a, b);
}

// expert of a padded m-tile: scan padded offsets
__device__ __forceinline__ int tile_expert(const int* eoff, int row0) {
  int e = 0;
#pragma unroll
  for (int i = 1; i < NEXP; ++i) if (row0 >= eoff[i]) e = i;
  return e;
}

// ---------------------------------------------------------------------------
// Kernel 3: grouped GEMM1 (EXACT r18 fused-f32 body + tile-major mapping;
// ONLY change: __launch_bounds__(256,5) -> up to 5 resident blocks/CU for
// latency hiding and tail smoothing). M128 x (64 gate + 64 up), silu fused.
// A bf16 gload_lds; B f32 reg-staged + cvt_pk + ds_write; 2-buffer pipeline.
// ---------------------------------------------------------------------------
__global__ __launch_bounds__(256, 5) void k_gateup(
    const short* __restrict__ xg, const float* __restrict__ w13,
    const int* __restrict__ eoff, short* __restrict__ act) {
  __shared__ __align__(16) short a_s[2][128 * 32];   // 8 KB x2
  __shared__ __align__(16) short bg_s[2][64 * 32];   // 4 KB x2
  __shared__ __align__(16) short bu_s[2][64 * 32];   // 4 KB x2

  int bxr = blockIdx.x;                       // 880 = 8 * 110 (XCD chunk)
  const int bx = (bxr & 7) * 110 + (bxr >> 3);
  const int tile = bx / 22;
  const int nt = bx - tile * 22;              // 0..21
  const int row0 = tile * 128;
  if (row0 >= eoff[NEXP]) return;
  const int e = tile_expert(eoff, row0);

  const int tid = threadIdx.x;
  const int wid = tid >> 6;
  const int lane = tid & 63;
  const int wm = wid >> 1, wn = wid & 1;

  f32x4 accg[4][2] = {};
  f32x4 accu[4][2] = {};

  const short* aG  = xg + (size_t)row0 * H_DIM;
  const float* bgG = w13 + (size_t)e * (2 * I_DIM) * H_DIM + (size_t)(nt * 64) * H_DIM;
  const float* buG = bgG + (size_t)I_DIM * H_DIM;

  const int row  = tid >> 2;                             // 0..63
  const int scol = ((tid & 3) ^ ((tid >> 3) & 3)) * 8;   // elems

  auto stageA = [&](int t, int bi) {
    const int ks = t * 32;
    load_lds16(aG + (size_t)row * H_DIM + ks + scol,        (char*)a_s[bi] + wid * 1024);
    load_lds16(aG + (size_t)(64 + row) * H_DIM + ks + scol, (char*)a_s[bi] + 4096 + wid * 1024);
  };

  f32x4 g0, g1, u0, u1;   // staged B regs (static names)
  auto ldB = [&](int t) {
    const int ks = t * 32;
    const float* sg = bgG + (size_t)row * H_DIM + ks + scol;
    const float* su = buG + (size_t)row * H_DIM + ks + scol;
    g0 = *(const f32x4*)sg; g1 = *(const f32x4*)(sg + 4);
    u0 = *(const f32x4*)su; u1 = *(const f32x4*)(su + 4);
  };
  auto wrB = [&](int bi) {
    *(short8*)((char*)bg_s[bi] + tid * 16) = cvt8(g0, g1);
    *(short8*)((char*)bu_s[bi] + tid * 16) = cvt8(u0, u1);
  };

  auto compute = [&](int bi) {
    const int asl = ((lane >> 4) ^ ((lane >> 1) & 3)) * 16;
    short8 af[4];
#pragma unroll
    for (int fm = 0; fm < 4; ++fm) {
      int m = wm * 64 + fm * 16 + (lane & 15);
      af[fm] = *(const short8*)((const char*)a_s[bi] + m * 64 + asl);
    }
#pragma unroll
    for (int fn = 0; fn < 2; ++fn) {
      int n = wn * 32 + fn * 16 + (lane & 15);
      short8 bg = *(const short8*)((const char*)bg_s[bi] + n * 64 + asl);
      short8 bu = *(const short8*)((const char*)bu_s[bi] + n * 64 + asl);
#pragma unroll
      for (int fm = 0; fm < 4; ++fm)
        accg[fm][fn] = __builtin_amdgcn_mfma_f32_16x16x32_bf16(af[fm], bg, accg[fm][fn], 0, 0, 0);
#pragma unroll
      for (int fm = 0; fm < 4; ++fm)
        accu[fm][fn] = __builtin_amdgcn_mfma_f32_16x16x32_bf16(af[fm], bu, accu[fm][fn], 0, 0, 0);
    }
  };

  const int NK = H_DIM / 32;  // 64
  stageA(0, 0); ldB(0); wrB(0);
  __syncthreads();
  for (int t = 0; t < NK; ++t) {
    int bi = t & 1;
    if (t + 1 < NK) { stageA(t + 1, bi ^ 1); ldB(t + 1); }
    compute(bi);
    if (t + 1 < NK) wrB(bi ^ 1);
    __syncthreads();
  }

  // epilogue: silu(g)*u -> bf16 act (rows padded, no bounds check)
#pragma unroll
  for (int fm = 0; fm < 4; ++fm) {
#pragma unroll
    for (int rr = 0; rr < 4; ++rr) {
      int m = wm * 64 + fm * 16 + (lane >> 4) * 4 + rr;
      size_t grow = (size_t)(row0 + m);
#pragma unroll
      for (int fn = 0; fn < 2; ++fn) {
        int col = nt * 64 + wn * 32 + fn * 16 + (lane & 15);
        float g = accg[fm][fn][rr];
        float u = accu[fm][fn][rr];
        float a = g / (1.f + __expf(-g)) * u;
        act[grow * I_DIM + col] = f2bf(a);
      }
    }
  }
}

// ---------------------------------------------------------------------------
// Kernel 4: grouped GEMM2 (EXACT r10/r18 counted-vmcnt fused version, bf16 y):
// y[pos] = act @ w2[e]^T. A bf16 gload_lds; B f32 reg-staged + cvt_pk,
// B regs double-buffered 3 steps ahead, end-of-step vmcnt(4).
// ---------------------------------------------------------------------------
__global__ __launch_bounds__(256, 3) void k_down(
    const short* __restrict__ act, const float* __restrict__ w2,
    const int* __restrict__ eoff, short* __restrict__ y) {
  __shared__ __align__(16) short a_s[2][128 * 32];  // 8 KB x2
  __shared__ __align__(16) short b_s[2][128 * 32];  // 8 KB x2

  int bxr = blockIdx.x;                       // 640 = 8 * 80 (XCD chunk)
  const int bx = (bxr & 7) * 80 + (bxr >> 3);
  const int tile = bx >> 4;
  const int nt = bx & 15;                     // 0..15 (128-wide h tile)
  const int row0 = tile * 128;
  if (row0 >= eoff[NEXP]) return;
  const int e = tile_expert(eoff, row0);

  const int tid = threadIdx.x;
  const int wid = tid >> 6;
  const int lane = tid & 63;
  const int wm = wid >> 1, wn = wid & 1;

  f32x4 acc[4][4] = {};

  const short* aG = act + (size_t)row0 * I_DIM;
  const float* bG = w2 + (size_t)e * H_DIM * I_DIM + (size_t)(nt * 128) * I_DIM;

  const int row  = tid >> 2;
  const int scol = ((tid & 3) ^ ((tid >> 3) & 3)) * 8;

  auto stageA = [&](int t, int bi) {   // 2 gload_lds
    const int ks = t * 32;
    load_lds16(aG + (size_t)row * I_DIM + ks + scol,        (char*)a_s[bi] + wid * 1024);
    load_lds16(aG + (size_t)(64 + row) * I_DIM + ks + scol, (char*)a_s[bi] + 4096 + wid * 1024);
  };
  auto ldB = [&](int t, f32x4& b00, f32x4& b01, f32x4& b10, f32x4& b11) {  // 4 loads
    const int ks = t * 32;
    const float* s0 = bG + (size_t)row * I_DIM + ks + scol;
    const float* s1 = bG + (size_t)(64 + row) * I_DIM + ks + scol;
    b00 = *(const f32x4*)s0; b01 = *(const f32x4*)(s0 + 4);
    b10 = *(const f32x4*)s1; b11 = *(const f32x4*)(s1 + 4);
  };
  auto wrB = [&](int bi, f32x4& b00, f32x4& b01, f32x4& b10, f32x4& b11) {
    *(short8*)((char*)b_s[bi] + tid * 16)        = cvt8(b00, b01);
    *(short8*)((char*)b_s[bi] + 4096 + tid * 16) = cvt8(b10, b11);
  };

  auto compute = [&](int bi) {
    const int asl = ((lane >> 4) ^ ((lane >> 1) & 3)) * 16;
    short8 af[4];
#pragma unroll
    for (int fm = 0; fm < 4; ++fm) {
      int m = wm * 64 + fm * 16 + (lane & 15);
      af[fm] = *(const short8*)((const char*)a_s[bi] + m * 64 + asl);
    }
#pragma unroll
    for (int fn = 0; fn < 4; ++fn) {
      int n = wn * 64 + fn * 16 + (lane & 15);
      short8 bb = *(const short8*)((const char*)b_s[bi] + n * 64 + asl);
#pragma unroll
      for (int fm = 0; fm < 4; ++fm)
        acc[fm][fn] = __builtin_amdgcn_mfma_f32_16x16x32_bf16(af[fm], bb, acc[fm][fn], 0, 0, 0);
    }
  };

  const int NK = I_DIM / 32;  // 44 (even)
  f32x4 e0, e1, e2, e3, o0, o1, o2, o3;

  stageA(0, 0);
  ldB(0, e0, e1, e2, e3);
  wrB(0, e0, e1, e2, e3);
  ldB(1, e0, e1, e2, e3);
  ldB(2, o0, o1, o2, o3);
  __syncthreads();

#define DN_STEP(T, B0, B1, B2, B3)                                            \
  {                                                                           \
    const int t_ = (T);                                                       \
    const int bi_ = t_ & 1;                                                   \
    const int tn_ = (t_ + 1 < NK) ? t_ + 1 : NK - 1;                          \
    const int tf_ = (t_ + 3 < NK) ? t_ + 3 : NK - 1;                          \
    stageA(tn_, bi_ ^ 1);                                                     \
    __builtin_amdgcn_sched_barrier(0);                                        \
    wrB(bi_ ^ 1, B0, B1, B2, B3);                                             \
    ldB(tf_, B0, B1, B2, B3);                                                 \
    compute(bi_);                                                             \
    asm volatile("s_waitcnt vmcnt(4) lgkmcnt(0)" ::: "memory");               \
    __builtin_amdgcn_s_barrier();                                             \
  }
  for (int tp = 0; tp < NK; tp += 2) {
    DN_STEP(tp,     e0, e1, e2, e3);
    DN_STEP(tp + 1, o0, o1, o2, o3);
  }
#undef DN_STEP
  asm volatile("s_waitcnt vmcnt(0)" ::: "memory");

#pragma unroll
  for (int fm = 0; fm < 4; ++fm) {
#pragma unroll
    for (int rr = 0; rr < 4; ++rr) {
      int m = wm * 64 + fm * 16 + (lane >> 4) * 4 + rr;
      size_t grow = (size_t)(row0 + m);
#pragma unroll
      for (int fn = 0; fn < 4; ++fn) {
        int col = nt * 128 + wn * 64 + fn * 16 + (lane & 15);
        y[grow * H_DIM + col] = f2bf(acc[fm][fn][rr]);
      }
    }
  }
}

// ---------------------------------------------------------------------------
// Kernel 5: combine: out[t] = w(p0)*y[p0] + w(p1)*y[p1]. bf16 y, f32 out.
// ---------------------------------------------------------------------------
__global__ void k_combine(const short* __restrict__ y,
                          const int* __restrict__ inv,
                          const float* __restrict__ pos_w,
                          float* __restrict__ out) {
  const int t = blockIdx.x;
  const int tid = threadIdx.x;
  const int p0 = inv[2 * t], p1 = inv[2 * t + 1];
  const float w0 = pos_w[p0], w1 = pos_w[p1];
  short8 a = ((const short8*)(y + (size_t)p0 * H_DIM))[tid];
  short8 b = ((const short8*)(y + (size_t)p1 * H_DIM))[tid];
  f32x4 r0, r1;
#pragma unroll
  for (int j = 0; j < 4; ++j) {
    r0[j] = w0 * bf2f(a[j]) + w1 * bf2f(b[j]);
    r1[j] = w0 * bf2f(a[j + 4]) + w1 * bf2f(b[j + 4]);
  }
  f32x4* o = (f32x4*)(out + (size_t)t * H_DIM);
  o[tid * 2]     = r0;
  o[tid * 2 + 1] = r1;
}

// ---------------------------------------------------------------------------
extern "C" void kernel_launch(void* const* d_in, const int* in_sizes, int n_in,
                              void* d_out, int out_size, void* d_ws, size_t ws_size,
                              hipStream_t stream) {
  const float* x      = (const float*)d_in[0];
  const float* logits = (const float*)d_in[1];
  const float* w13    = (const float*)d_in[2];
  const float* w2     = (const float*)d_in[3];
  (void)in_sizes; (void)n_in; (void)out_size; (void)ws_size;
  float* out = (float*)d_out;
  char* ws = (char*)d_ws;

  size_t o = 0;
  auto alloc = [&](size_t bytes) { size_t r = o; o += (bytes + 255) & ~(size_t)255; return r; };
  short* xg        = (short*)(ws + alloc((size_t)NPAD * H_DIM * 2));   // 21.0 MB
  short* act       = (short*)(ws + alloc((size_t)NPAD * I_DIM * 2));   // 14.4 MB
  short* y         = (short*)(ws + alloc((size_t)NPAD * H_DIM * 2));   // 21.0 MB
  int*   pos_token = (int*)  (ws + alloc((size_t)NPAD * 4));
  float* pos_w     = (float*)(ws + alloc((size_t)NPAD * 4));
  int*   inv       = (int*)  (ws + alloc((size_t)T_TOK * 2 * 4));
  int*   eoff      = (int*)  (ws + alloc((NEXP + 1) * 4));

  k_routing<<<1, 1024, 0, stream>>>(logits, pos_token, pos_w, eoff, inv);
  k_gather<<<NPAD, 256, 0, stream>>>(x, pos_token, xg);
  k_gateup<<<MAXT * 22, 256, 0, stream>>>(xg, w13, eoff, act);
  k_down<<<MAXT * 16, 256, 0, stream>>>(act, w2, eoff, y);
  k_combine<<<T_TOK, 256, 0, stream>>>(y, inv, pos_w, out);
}

// Round 21
// 212.784 us; speedup vs baseline: 1.1214x; 1.1214x over previous
//
#include <hip/hip_runtime.h>
#include <hip/hip_bf16.h>
#include <stdint.h>

#define T_TOK 2048
#define H_DIM 2048
#define I_DIM 1408
#define GU_W  2816   // 2*I_DIM rows of w13 per expert
#define NEXP  8
#define NPOS  4096   // T_TOK * top_k
#define NPAD  5120   // max padded rows: 4096 + 8*128
#define MAXT  40     // NPAD / 128

typedef short short8 __attribute__((ext_vector_type(8)));
typedef float f32x4  __attribute__((ext_vector_type(4)));

// f32 -> bf16 RNE (finite inputs only)
__device__ __forceinline__ short f2bf(float f) {
  union { float f; uint32_t u; } v; v.f = f;
  uint32_t r = (v.u + 0x7FFFu + ((v.u >> 16) & 1u)) >> 16;
  return (short)r;
}
__device__ __forceinline__ float bf2f(short s) {
  union { uint32_t u; float f; } v; v.u = ((uint32_t)(uint16_t)s) << 16;
  return v.f;
}

// 8x f32 -> bf16 via packed HW cvt (v_cvt_pk_bf16_f32), RNE — matches f2bf
__device__ __forceinline__ short8 cvt8(f32x4 a, f32x4 b) {
  __hip_bfloat162 h0 = __float22bfloat162_rn(float2{a[0], a[1]});
  __hip_bfloat162 h1 = __float22bfloat162_rn(float2{a[2], a[3]});
  __hip_bfloat162 h2 = __float22bfloat162_rn(float2{b[0], b[1]});
  __hip_bfloat162 h3 = __float22bfloat162_rn(float2{b[2], b[3]});
  short2 s0, s1, s2, s3;
  __builtin_memcpy(&s0, &h0, 4); __builtin_memcpy(&s1, &h1, 4);
  __builtin_memcpy(&s2, &h2, 4); __builtin_memcpy(&s3, &h3, 4);
  short8 r;
  r[0] = s0.x; r[1] = s0.y; r[2] = s1.x; r[3] = s1.y;
  r[4] = s2.x; r[5] = s2.y; r[6] = s3.x; r[7] = s3.y;
  return r;
}

// async global->LDS, 16B per lane. LDS dest = wave-uniform base + lane*16.
__device__ __forceinline__ void load_lds16(const void* g, void* l) {
  __builtin_amdgcn_global_load_lds((const __attribute__((address_space(1))) uint32_t*)g,
                                   (__attribute__((address_space(3))) uint32_t*)l,
                                   16, 0, 0);
}

// ---------------------------------------------------------------------------
// Kernel 1: routing. Single block, 1024 threads. Top-2 of 8 logits,
// 128-PADDED per-expert grouping. Pad slots: token 0, weight 0 (self-masking).
// Emits inverse map inv[2t], inv[2t+1] = the two pos slots of token t.
// ---------------------------------------------------------------------------
__global__ void k_routing(const float* __restrict__ logits,
                          int* __restrict__ pos_token,
                          float* __restrict__ pos_w,
                          int* __restrict__ eoff,
                          int* __restrict__ inv) {
  __shared__ int   s_ids[T_TOK];
  __shared__ float s_w0[T_TOK];
  __shared__ float s_w1[T_TOK];
  __shared__ int s_cnt[NEXP], s_cur[NEXP], s_off[NEXP + 1];
  const int tid = threadIdx.x;
  if (tid < NEXP) { s_cnt[tid] = 0; s_cur[tid] = 0; }
  for (int p = tid; p < NPAD; p += blockDim.x) { pos_token[p] = 0; pos_w[p] = 0.f; }
  __syncthreads();

  for (int t = tid; t < T_TOK; t += blockDim.x) {
    float l[NEXP];
#pragma unroll
    for (int e = 0; e < NEXP; ++e) l[e] = logits[t * NEXP + e];
    int b0 = 0; float v0 = l[0];
#pragma unroll
    for (int e = 1; e < NEXP; ++e) if (l[e] > v0) { v0 = l[e]; b0 = e; }
    int b1 = -1; float v1 = -1e30f;
#pragma unroll
    for (int e = 0; e < NEXP; ++e) if (e != b0 && l[e] > v1) { v1 = l[e]; b1 = e; }
    float t1 = __expf(v1 - v0);
    float w0 = 1.f / (1.f + t1);
    float w1 = 1.f - w0;
    s_ids[t] = b0 | (b1 << 8);
    s_w0[t] = w0; s_w1[t] = w1;
    atomicAdd(&s_cnt[b0], 1);
    atomicAdd(&s_cnt[b1], 1);
  }
  __syncthreads();
  if (tid == 0) {
    int acc = 0;
    for (int e = 0; e < NEXP; ++e) {
      s_off[e] = acc;
      acc += (s_cnt[e] + 127) & ~127;   // 128-padded
    }
    s_off[NEXP] = acc;
    for (int e = 0; e <= NEXP; ++e) eoff[e] = s_off[e];
  }
  __syncthreads();
  for (int t = tid; t < T_TOK; t += blockDim.x) {
    int ids = s_ids[t];
    int e0 = ids & 255, e1 = ids >> 8;
    int p0 = s_off[e0] + atomicAdd(&s_cur[e0], 1);
    pos_token[p0] = t; pos_w[p0] = s_w0[t];
    int p1 = s_off[e1] + atomicAdd(&s_cur[e1], 1);
    pos_token[p1] = t; pos_w[p1] = s_w1[t];
    inv[2 * t] = p0; inv[2 * t + 1] = p1;
  }
}

// ---------------------------------------------------------------------------
// Kernel 2: gather+cast x rows into grouped (padded) order, bf16.
// ---------------------------------------------------------------------------
__global__ void k_gather(const float* __restrict__ x,
                         const int* __restrict__ pos_token,
                         short* __restrict__ xg) {
  const int p = blockIdx.x;
  const int tid = threadIdx.x;
  const int tok = pos_token[p];
  const f32x4* src = (const f32x4*)(x + (size_t)tok * H_DIM);
  f32x4 a = src[tid * 2];
  f32x4 b = src[tid * 2 + 1];
  ((short8*)(xg + (size_t)p * H_DIM))[tid] = cvt8(a, b);
}

// expert of a padded m-tile: scan padded offsets
__device__ __forceinline__ int tile_expert(const int* eoff, int row0) {
  int e = 0;
#pragma unroll
  for (int i = 1; i < NEXP; ++i) if (row0 >= eoff[i]) e = i;
  return e;
}

// ---------------------------------------------------------------------------
// Kernel 3: grouped GEMM1, SINGLE-PASS WEIGHTS: block = (expert, nt); each
// (e,nt) w13 panel (64 gate + 64 up rows) is read by EXACTLY ONE block ->
// weight HBM traffic collapses 925 -> 185 MB (the minimum). M=640 (whole
// padded expert, chunk-looped for skew-robustness), 512 threads = 8 waves,
// each wave 80 rows x 128 cols (acc 40 x f32x4 = 160 VGPR).
// A bf16 via gload_lds (40 KB/step, XOR-swizzled); B f32 reg-staged + cvt_pk
// (half-block per panel). Per wave-step: 13 ds_read_b128 : 40 MFMA.
// ---------------------------------------------------------------------------
__global__ __launch_bounds__(512, 1) void k_gateup(
    const short* __restrict__ xg, const float* __restrict__ w13,
    const int* __restrict__ eoff, short* __restrict__ act) {
  __shared__ __align__(16) short a_s[2][640 * 32];   // 40 KB x2
  __shared__ __align__(16) short bg_s[2][64 * 32];   // 4 KB x2
  __shared__ __align__(16) short bu_s[2][64 * 32];   // 4 KB x2

  const int bxr = blockIdx.x;          // 176 = 8 experts x 22 nt
  const int e = bxr & 7;               // expert per XCD slot
  const int nt = bxr >> 3;             // 0..21
  const int off = eoff[e], end = eoff[e + 1];

  const int tid = threadIdx.x;
  const int wid = tid >> 6;            // 0..7
  const int lane = tid & 63;

  const float* bgG = w13 + (size_t)e * GU_W * H_DIM + (size_t)(nt * 64) * H_DIM;
  const float* buG = bgG + (size_t)I_DIM * H_DIM;

  // A staging coords: 5 rounds of 128 rows; inverse-swizzled source col.
  const int arow = tid >> 2;                             // 0..127
  const int scol = ((tid & 3) ^ ((tid >> 3) & 3)) * 8;   // bf16 elems
  // B staging coords: half-block per panel (gate | up)
  const int t2 = tid & 255;
  const int brow = t2 >> 2;                              // 0..63
  const int bscol = ((t2 & 3) ^ ((t2 >> 3) & 3)) * 8;    // f32 elems
  const float* bHalf = (tid < 256) ? bgG : buG;

  for (int base = off; base < end; base += 640) {
    f32x4 accg[5][4] = {};
    f32x4 accu[5][4] = {};

    auto stageA = [&](int t, int bi) {   // 5 gload_lds per thread
      const int ks = t * 32;
#pragma unroll
      for (int r = 0; r < 5; ++r) {
        int gr = base + r * 128 + arow;
        if (gr > NPAD - 1) gr = NPAD - 1;   // clamp (stay in-bounds)
        load_lds16(xg + (size_t)gr * H_DIM + ks + scol,
                   (char*)a_s[bi] + r * 8192 + wid * 1024);
      }
    };

    f32x4 b0, b1;
    auto ldB = [&](int t) {
      const int ks = t * 32;
      const float* s = bHalf + (size_t)brow * H_DIM + ks + bscol;
      b0 = *(const f32x4*)s; b1 = *(const f32x4*)(s + 4);
    };
    auto wrB = [&](int bi) {
      char* d = (tid < 256) ? (char*)bg_s[bi] : (char*)bu_s[bi];
      *(short8*)(d + t2 * 16) = cvt8(b0, b1);
    };

    auto compute = [&](int bi) {
      const int asl = ((lane >> 4) ^ ((lane >> 1) & 3)) * 16;
      short8 af[5];
#pragma unroll
      for (int fm = 0; fm < 5; ++fm) {
        int m = wid * 80 + fm * 16 + (lane & 15);
        af[fm] = *(const short8*)((const char*)a_s[bi] + m * 64 + asl);
      }
#pragma unroll
      for (int fn = 0; fn < 4; ++fn) {
        int n = fn * 16 + (lane & 15);
        short8 bg = *(const short8*)((const char*)bg_s[bi] + n * 64 + asl);
        short8 bu = *(const short8*)((const char*)bu_s[bi] + n * 64 + asl);
#pragma unroll
        for (int fm = 0; fm < 5; ++fm)
          accg[fm][fn] = __builtin_amdgcn_mfma_f32_16x16x32_bf16(af[fm], bg, accg[fm][fn], 0, 0, 0);
#pragma unroll
        for (int fm = 0; fm < 5; ++fm)
          accu[fm][fn] = __builtin_amdgcn_mfma_f32_16x16x32_bf16(af[fm], bu, accu[fm][fn], 0, 0, 0);
      }
    };

    const int NK = H_DIM / 32;  // 64
    stageA(0, 0); ldB(0); wrB(0);
    __syncthreads();
    for (int t = 0; t < NK; ++t) {
      int bi = t & 1;
      if (t + 1 < NK) { stageA(t + 1, bi ^ 1); ldB(t + 1); }
      compute(bi);
      if (t + 1 < NK) wrB(bi ^ 1);
      __syncthreads();
    }

    // epilogue: silu(g)*u -> bf16 act; store guarded to this expert's region
#pragma unroll
    for (int fm = 0; fm < 5; ++fm) {
#pragma unroll
      for (int rr = 0; rr < 4; ++rr) {
        int m = wid * 80 + fm * 16 + (lane >> 4) * 4 + rr;
        int grow = base + m;
        if (grow < end) {
#pragma unroll
          for (int fn = 0; fn < 4; ++fn) {
            int col = nt * 64 + fn * 16 + (lane & 15);
            float g = accg[fm][fn][rr];
            float u = accu[fm][fn][rr];
            float a = g / (1.f + __expf(-g)) * u;
            act[(size_t)grow * I_DIM + col] = f2bf(a);
          }
        }
      }
    }
    // epilogue touches no LDS; next chunk's stageA+syncthreads is safe
  }
}

// ---------------------------------------------------------------------------
// Kernel 4: grouped GEMM2 (EXACT r18 counted-vmcnt fused version, bf16 y):
// y[pos] = act @ w2[e]^T. A bf16 gload_lds; B f32 reg-staged + cvt_pk,
// B regs double-buffered 3 steps ahead, end-of-step vmcnt(4).
// ---------------------------------------------------------------------------
__global__ __launch_bounds__(256, 3) void k_down(
    const short* __restrict__ act, const float* __restrict__ w2,
    const int* __restrict__ eoff, short* __restrict__ y) {
  __shared__ __align__(16) short a_s[2][128 * 32];  // 8 KB x2
  __shared__ __align__(16) short b_s[2][128 * 32];  // 8 KB x2

  int bxr = blockIdx.x;                       // 640 = 8 * 80 (XCD chunk)
  const int bx = (bxr & 7) * 80 + (bxr >> 3);
  const int tile = bx >> 4;
  const int nt = bx & 15;                     // 0..15 (128-wide h tile)
  const int row0 = tile * 128;
  if (row0 >= eoff[NEXP]) return;
  const int e = tile_expert(eoff, row0);

  const int tid = threadIdx.x;
  const int wid = tid >> 6;
  const int lane = tid & 63;
  const int wm = wid >> 1, wn = wid & 1;

  f32x4 acc[4][4] = {};

  const short* aG = act + (size_t)row0 * I_DIM;
  const float* bG = w2 + (size_t)e * H_DIM * I_DIM + (size_t)(nt * 128) * I_DIM;

  const int row  = tid >> 2;
  const int scol = ((tid & 3) ^ ((tid >> 3) & 3)) * 8;

  auto stageA = [&](int t, int bi) {   // 2 gload_lds
    const int ks = t * 32;
    load_lds16(aG + (size_t)row * I_DIM + ks + scol,        (char*)a_s[bi] + wid * 1024);
    load_lds16(aG + (size_t)(64 + row) * I_DIM + ks + scol, (char*)a_s[bi] + 4096 + wid * 1024);
  };
  auto ldB = [&](int t, f32x4& b00, f32x4& b01, f32x4& b10, f32x4& b11) {  // 4 loads
    const int ks = t * 32;
    const float* s0 = bG + (size_t)row * I_DIM + ks + scol;
    const float* s1 = bG + (size_t)(64 + row) * I_DIM + ks + scol;
    b00 = *(const f32x4*)s0; b01 = *(const f32x4*)(s0 + 4);
    b10 = *(const f32x4*)s1; b11 = *(const f32x4*)(s1 + 4);
  };
  auto wrB = [&](int bi, f32x4& b00, f32x4& b01, f32x4& b10, f32x4& b11) {
    *(short8*)((char*)b_s[bi] + tid * 16)        = cvt8(b00, b01);
    *(short8*)((char*)b_s[bi] + 4096 + tid * 16) = cvt8(b10, b11);
  };

  auto compute = [&](int bi) {
    const int asl = ((lane >> 4) ^ ((lane >> 1) & 3)) * 16;
    short8 af[4];
#pragma unroll
    for (int fm = 0; fm < 4; ++fm) {
      int m = wm * 64 + fm * 16 + (lane & 15);
      af[fm] = *(const short8*)((const char*)a_s[bi] + m * 64 + asl);
    }
#pragma unroll
    for (int fn = 0; fn < 4; ++fn) {
      int n = wn * 64 + fn * 16 + (lane & 15);
      short8 bb = *(const short8*)((const char*)b_s[bi] + n * 64 + asl);
#pragma unroll
      for (int fm = 0; fm < 4; ++fm)
        acc[fm][fn] = __builtin_amdgcn_mfma_f32_16x16x32_bf16(af[fm], bb, acc[fm][fn], 0, 0, 0);
    }
  };

  const int NK = I_DIM / 32;  // 44 (even)
  f32x4 e0, e1, e2, e3, o0, o1, o2, o3;

  stageA(0, 0);
  ldB(0, e0, e1, e2, e3);
  wrB(0, e0, e1, e2, e3);
  ldB(1, e0, e1, e2, e3);
  ldB(2, o0, o1, o2, o3);
  __syncthreads();

#define DN_STEP(T, B0, B1, B2, B3)                                            \
  {                                                                           \
    const int t_ = (T);                                                       \
    const int bi_ = t_ & 1;                                                   \
    const int tn_ = (t_ + 1 < NK) ? t_ + 1 : NK - 1;                          \
    const int tf_ = (t_ + 3 < NK) ? t_ + 3 : NK - 1;                          \
    stageA(tn_, bi_ ^ 1);                                                     \
    __builtin_amdgcn_sched_barrier(0);                                        \
    wrB(bi_ ^ 1, B0, B1, B2, B3);                                             \
    ldB(tf_, B0, B1, B2, B3);                                                 \
    compute(bi_);                                                             \
    asm volatile("s_waitcnt vmcnt(4) lgkmcnt(0)" ::: "memory");               \
    __builtin_amdgcn_s_barrier();                                             \
  }
  for (int tp = 0; tp < NK; tp += 2) {
    DN_STEP(tp,     e0, e1, e2, e3);
    DN_STEP(tp + 1, o0, o1, o2, o3);
  }
#undef DN_STEP
  asm volatile("s_waitcnt vmcnt(0)" ::: "memory");

#pragma unroll
  for (int fm = 0; fm < 4; ++fm) {
#pragma unroll
    for (int rr = 0; rr < 4; ++rr) {
      int m = wm * 64 + fm * 16 + (lane >> 4) * 4 + rr;
      size_t grow = (size_t)(row0 + m);
#pragma unroll
      for (int fn = 0; fn < 4; ++fn) {
        int col = nt * 128 + wn * 64 + fn * 16 + (lane & 15);
        y[grow * H_DIM + col] = f2bf(acc[fm][fn][rr]);
      }
    }
  }
}

// ---------------------------------------------------------------------------
// Kernel 5: combine: out[t] = w(p0)*y[p0] + w(p1)*y[p1]. bf16 y, f32 out.
// ---------------------------------------------------------------------------
__global__ void k_combine(const short* __restrict__ y,
                          const int* __restrict__ inv,
                          const float* __restrict__ pos_w,
                          float* __restrict__ out) {
  const int t = blockIdx.x;
  const int tid = threadIdx.x;
  const int p0 = inv[2 * t], p1 = inv[2 * t + 1];
  const float w0 = pos_w[p0], w1 = pos_w[p1];
  short8 a = ((const short8*)(y + (size_t)p0 * H_DIM))[tid];
  short8 b = ((const short8*)(y + (size_t)p1 * H_DIM))[tid];
  f32x4 r0, r1;
#pragma unroll
  for (int j = 0; j < 4; ++j) {
    r0[j] = w0 * bf2f(a[j]) + w1 * bf2f(b[j]);
    r1[j] = w0 * bf2f(a[j + 4]) + w1 * bf2f(b[j + 4]);
  }
  f32x4* o = (f32x4*)(out + (size_t)t * H_DIM);
  o[tid * 2]     = r0;
  o[tid * 2 + 1] = r1;
}

// ---------------------------------------------------------------------------
extern "C" void kernel_launch(void* const* d_in, const int* in_sizes, int n_in,
                              void* d_out, int out_size, void* d_ws, size_t ws_size,
                              hipStream_t stream) {
  const float* x      = (const float*)d_in[0];
  const float* logits = (const float*)d_in[1];
  const float* w13    = (const float*)d_in[2];
  const float* w2     = (const float*)d_in[3];
  (void)in_sizes; (void)n_in; (void)out_size; (void)ws_size;
  float* out = (float*)d_out;
  char* ws = (char*)d_ws;

  size_t o = 0;
  auto alloc = [&](size_t bytes) { size_t r = o; o += (bytes + 255) & ~(size_t)255; return r; };
  short* xg        = (short*)(ws + alloc((size_t)NPAD * H_DIM * 2));   // 21.0 MB
  short* act       = (short*)(ws + alloc((size_t)NPAD * I_DIM * 2));   // 14.4 MB
  short* y         = (short*)(ws + alloc((size_t)NPAD * H_DIM * 2));   // 21.0 MB
  int*   pos_token = (int*)  (ws + alloc((size_t)NPAD * 4));
  float* pos_w     = (float*)(ws + alloc((size_t)NPAD * 4));
  int*   inv       = (int*)  (ws + alloc((size_t)T_TOK * 2 * 4));
  int*   eoff      = (int*)  (ws + alloc((NEXP + 1) * 4));

  k_routing<<<1, 1024, 0, stream>>>(logits, pos_token, pos_w, eoff, inv);
  k_gather<<<NPAD, 256, 0, stream>>>(x, pos_token, xg);
  k_gateup<<<NEXP * 22, 512, 0, stream>>>(xg, w13, eoff, act);
  k_down<<<MAXT * 16, 256, 0, stream>>>(act, w2, eoff, y);
  k_combine<<<T_TOK, 256, 0, stream>>>(y, inv, pos_w, out);
}

// Round 22
// 196.355 us; speedup vs baseline: 1.2152x; 1.0837x over previous
//
#include <hip/hip_runtime.h>
#include <hip/hip_bf16.h>
#include <stdint.h>

#define T_TOK 2048
#define H_DIM 2048
#define I_DIM 1408
#define GU_W  2816   // 2*I_DIM rows of w13 per expert
#define NEXP  8
#define NPOS  4096   // T_TOK * top_k
#define NPAD  5120   // max padded rows: 4096 + 8*128
#define MAXT  40     // NPAD / 128

typedef short short8 __attribute__((ext_vector_type(8)));
typedef float f32x4  __attribute__((ext_vector_type(4)));

// f32 -> bf16 RNE (finite inputs only)
__device__ __forceinline__ short f2bf(float f) {
  union { float f; uint32_t u; } v; v.f = f;
  uint32_t r = (v.u + 0x7FFFu + ((v.u >> 16) & 1u)) >> 16;
  return (short)r;
}
__device__ __forceinline__ float bf2f(short s) {
  union { uint32_t u; float f; } v; v.u = ((uint32_t)(uint16_t)s) << 16;
  return v.f;
}

// 8x f32 -> bf16 via packed HW cvt (v_cvt_pk_bf16_f32), RNE — matches f2bf
__device__ __forceinline__ short8 cvt8(f32x4 a, f32x4 b) {
  __hip_bfloat162 h0 = __float22bfloat162_rn(float2{a[0], a[1]});
  __hip_bfloat162 h1 = __float22bfloat162_rn(float2{a[2], a[3]});
  __hip_bfloat162 h2 = __float22bfloat162_rn(float2{b[0], b[1]});
  __hip_bfloat162 h3 = __float22bfloat162_rn(float2{b[2], b[3]});
  short2 s0, s1, s2, s3;
  __builtin_memcpy(&s0, &h0, 4); __builtin_memcpy(&s1, &h1, 4);
  __builtin_memcpy(&s2, &h2, 4); __builtin_memcpy(&s3, &h3, 4);
  short8 r;
  r[0] = s0.x; r[1] = s0.y; r[2] = s1.x; r[3] = s1.y;
  r[4] = s2.x; r[5] = s2.y; r[6] = s3.x; r[7] = s3.y;
  return r;
}

// async global->LDS, 16B per lane. LDS dest = wave-uniform base + lane*16.
__device__ __forceinline__ void load_lds16(const void* g, void* l) {
  __builtin_amdgcn_global_load_lds((const __attribute__((address_space(1))) uint32_t*)g,
                                   (__attribute__((address_space(3))) uint32_t*)l,
                                   16, 0, 0);
}

// ---------------------------------------------------------------------------
// Kernel 1: routing. Single block, 1024 threads. Top-2 of 8 logits,
// 128-PADDED per-expert grouping. Pad slots: token 0, weight 0 (self-masking).
// Emits inverse map inv[2t], inv[2t+1] = the two pos slots of token t.
// ---------------------------------------------------------------------------
__global__ void k_routing(const float* __restrict__ logits,
                          int* __restrict__ pos_token,
                          float* __restrict__ pos_w,
                          int* __restrict__ eoff,
                          int* __restrict__ inv) {
  __shared__ int   s_ids[T_TOK];
  __shared__ float s_w0[T_TOK];
  __shared__ float s_w1[T_TOK];
  __shared__ int s_cnt[NEXP], s_cur[NEXP], s_off[NEXP + 1];
  const int tid = threadIdx.x;
  if (tid < NEXP) { s_cnt[tid] = 0; s_cur[tid] = 0; }
  for (int p = tid; p < NPAD; p += blockDim.x) { pos_token[p] = 0; pos_w[p] = 0.f; }
  __syncthreads();

  for (int t = tid; t < T_TOK; t += blockDim.x) {
    float l[NEXP];
#pragma unroll
    for (int e = 0; e < NEXP; ++e) l[e] = logits[t * NEXP + e];
    int b0 = 0; float v0 = l[0];
#pragma unroll
    for (int e = 1; e < NEXP; ++e) if (l[e] > v0) { v0 = l[e]; b0 = e; }
    int b1 = -1; float v1 = -1e30f;
#pragma unroll
    for (int e = 0; e < NEXP; ++e) if (e != b0 && l[e] > v1) { v1 = l[e]; b1 = e; }
    float t1 = __expf(v1 - v0);
    float w0 = 1.f / (1.f + t1);
    float w1 = 1.f - w0;
    s_ids[t] = b0 | (b1 << 8);
    s_w0[t] = w0; s_w1[t] = w1;
    atomicAdd(&s_cnt[b0], 1);
    atomicAdd(&s_cnt[b1], 1);
  }
  __syncthreads();
  if (tid == 0) {
    int acc = 0;
    for (int e = 0; e < NEXP; ++e) {
      s_off[e] = acc;
      acc += (s_cnt[e] + 127) & ~127;   // 128-padded
    }
    s_off[NEXP] = acc;
    for (int e = 0; e <= NEXP; ++e) eoff[e] = s_off[e];
  }
  __syncthreads();
  for (int t = tid; t < T_TOK; t += blockDim.x) {
    int ids = s_ids[t];
    int e0 = ids & 255, e1 = ids >> 8;
    int p0 = s_off[e0] + atomicAdd(&s_cur[e0], 1);
    pos_token[p0] = t; pos_w[p0] = s_w0[t];
    int p1 = s_off[e1] + atomicAdd(&s_cur[e1], 1);
    pos_token[p1] = t; pos_w[p1] = s_w1[t];
    inv[2 * t] = p0; inv[2 * t + 1] = p1;
  }
}

// ---------------------------------------------------------------------------
// Kernel 2: gather+cast x rows into grouped (padded) order, bf16.
// ---------------------------------------------------------------------------
__global__ void k_gather(const float* __restrict__ x,
                         const int* __restrict__ pos_token,
                         short* __restrict__ xg) {
  const int p = blockIdx.x;
  const int tid = threadIdx.x;
  const int tok = pos_token[p];
  const f32x4* src = (const f32x4*)(x + (size_t)tok * H_DIM);
  f32x4 a = src[tid * 2];
  f32x4 b = src[tid * 2 + 1];
  ((short8*)(xg + (size_t)p * H_DIM))[tid] = cvt8(a, b);
}

// expert of a padded m-tile: scan padded offsets
__device__ __forceinline__ int tile_expert(const int* eoff, int row0) {
  int e = 0;
#pragma unroll
  for (int i = 1; i < NEXP; ++i) if (row0 >= eoff[i]) e = i;
  return e;
}

// ---------------------------------------------------------------------------
// Kernel 3: grouped GEMM1, NEAR-SINGLE-PASS weights + counted-vmcnt pipeline.
// Block = (expert, nt, half): M=320 rows, full (64g+64u) panel; each w13
// panel read by exactly TWO blocks (~200 MB total weight traffic).
// 256 threads / 4 waves; wave = 80 rows x (64g+64u): acc[5][4]x2.
// Per K32-step: issue [A(t+1) x5 gload_lds][B(t+3) x4 reg loads], compute
// 40 MFMA, end-of-step s_waitcnt vmcnt(4) (B(t+3) stays in flight) —
// the schedule proven on k_down. B regs 2-set (E/O), static names.
// ---------------------------------------------------------------------------
__global__ __launch_bounds__(256, 2) void k_gateup(
    const short* __restrict__ xg, const float* __restrict__ w13,
    const int* __restrict__ eoff, short* __restrict__ act) {
  __shared__ __align__(16) short a_s[2][320 * 32];   // 20 KB x2
  __shared__ __align__(16) short bg_s[2][64 * 32];   // 4 KB x2
  __shared__ __align__(16) short bu_s[2][64 * 32];   // 4 KB x2

  const int bxr = blockIdx.x;          // 352 = 8 experts x 22 nt x 2 halves
  const int e = bxr & 7;               // expert per XCD slot
  const int r = bxr >> 3;              // 0..43
  const int nt = r >> 1;               // 0..21
  const int half = r & 1;
  const int off = eoff[e], end = eoff[e + 1];
  const int base = off + half * 320;
  if (base >= end) return;

  const int tid = threadIdx.x;
  const int wid = tid >> 6;            // 0..3
  const int lane = tid & 63;

  const float* bgG = w13 + (size_t)e * GU_W * H_DIM + (size_t)(nt * 64) * H_DIM;
  const float* buG = bgG + (size_t)I_DIM * H_DIM;

  // A staging: 5 rounds of 64 rows; inverse-swizzled source col.
  const int arow = tid >> 2;                             // 0..63
  const int scol = ((tid & 3) ^ ((tid >> 3) & 3)) * 8;   // elems (bf16/f32)

  f32x4 accg[5][4] = {};
  f32x4 accu[5][4] = {};

  auto stageA = [&](int t, int bi) {   // 5 gload_lds per thread
    const int ks = t * 32;
#pragma unroll
    for (int rr = 0; rr < 5; ++rr) {
      int gr = base + rr * 64 + arow;
      if (gr > NPAD - 1) gr = NPAD - 1;   // clamp (stay in-bounds)
      load_lds16(xg + (size_t)gr * H_DIM + ks + scol,
                 (char*)a_s[bi] + rr * 4096 + wid * 1024);
    }
  };
  auto ldB = [&](int t, f32x4& g0, f32x4& g1, f32x4& u0, f32x4& u1) {  // 4 loads
    const int ks = t * 32;
    const float* sg = bgG + (size_t)arow * H_DIM + ks + scol;
    const float* su = buG + (size_t)arow * H_DIM + ks + scol;
    g0 = *(const f32x4*)sg; g1 = *(const f32x4*)(sg + 4);
    u0 = *(const f32x4*)su; u1 = *(const f32x4*)(su + 4);
  };
  auto wrB = [&](int bi, f32x4& g0, f32x4& g1, f32x4& u0, f32x4& u1) {
    *(short8*)((char*)bg_s[bi] + tid * 16) = cvt8(g0, g1);
    *(short8*)((char*)bu_s[bi] + tid * 16) = cvt8(u0, u1);
  };

  auto compute = [&](int bi) {
    const int asl = ((lane >> 4) ^ ((lane >> 1) & 3)) * 16;
    short8 af[5];
#pragma unroll
    for (int fm = 0; fm < 5; ++fm) {
      int m = wid * 80 + fm * 16 + (lane & 15);
      af[fm] = *(const short8*)((const char*)a_s[bi] + m * 64 + asl);
    }
#pragma unroll
    for (int fn = 0; fn < 4; ++fn) {
      int n = fn * 16 + (lane & 15);
      short8 bg = *(const short8*)((const char*)bg_s[bi] + n * 64 + asl);
      short8 bu = *(const short8*)((const char*)bu_s[bi] + n * 64 + asl);
#pragma unroll
      for (int fm = 0; fm < 5; ++fm)
        accg[fm][fn] = __builtin_amdgcn_mfma_f32_16x16x32_bf16(af[fm], bg, accg[fm][fn], 0, 0, 0);
#pragma unroll
      for (int fm = 0; fm < 5; ++fm)
        accu[fm][fn] = __builtin_amdgcn_mfma_f32_16x16x32_bf16(af[fm], bu, accu[fm][fn], 0, 0, 0);
    }
  };

  const int NK = H_DIM / 32;  // 64 (even)
  f32x4 g0e, g1e, u0e, u1e, g0o, g1o, u0o, u1o;

  stageA(0, 0);
  ldB(0, g0e, g1e, u0e, u1e);
  wrB(0, g0e, g1e, u0e, u1e);
  ldB(1, g0e, g1e, u0e, u1e);
  ldB(2, g0o, g1o, u0o, u1o);
  __syncthreads();

#define GU_STEP(T, G0, G1, U0, U1)                                            \
  {                                                                           \
    const int t_ = (T);                                                       \
    const int bi_ = t_ & 1;                                                   \
    const int tn_ = (t_ + 1 < NK) ? t_ + 1 : NK - 1;                          \
    const int tf_ = (t_ + 3 < NK) ? t_ + 3 : NK - 1;                          \
    stageA(tn_, bi_ ^ 1);                                                     \
    __builtin_amdgcn_sched_barrier(0);                                        \
    wrB(bi_ ^ 1, G0, G1, U0, U1);                                             \
    ldB(tf_, G0, G1, U0, U1);                                                 \
    compute(bi_);                                                             \
    asm volatile("s_waitcnt vmcnt(4) lgkmcnt(0)" ::: "memory");               \
    __builtin_amdgcn_s_barrier();                                             \
  }
  for (int tp = 0; tp < NK; tp += 2) {
    GU_STEP(tp,     g0e, g1e, u0e, u1e);
    GU_STEP(tp + 1, g0o, g1o, u0o, u1o);
  }
#undef GU_STEP
  asm volatile("s_waitcnt vmcnt(0)" ::: "memory");

  // epilogue: silu(g)*u -> bf16 act; store guarded to this expert's region
#pragma unroll
  for (int fm = 0; fm < 5; ++fm) {
#pragma unroll
    for (int rr = 0; rr < 4; ++rr) {
      int m = wid * 80 + fm * 16 + (lane >> 4) * 4 + rr;
      int grow = base + m;
      if (grow < end) {
#pragma unroll
        for (int fn = 0; fn < 4; ++fn) {
          int col = nt * 64 + fn * 16 + (lane & 15);
          float g = accg[fm][fn][rr];
          float u = accu[fm][fn][rr];
          float a = g / (1.f + __expf(-g)) * u;
          act[(size_t)grow * I_DIM + col] = f2bf(a);
        }
      }
    }
  }
}

// ---------------------------------------------------------------------------
// Kernel 4: grouped GEMM2 (EXACT r18 counted-vmcnt fused version, bf16 y):
// y[pos] = act @ w2[e]^T. A bf16 gload_lds; B f32 reg-staged + cvt_pk,
// B regs double-buffered 3 steps ahead, end-of-step vmcnt(4).
// ---------------------------------------------------------------------------
__global__ __launch_bounds__(256, 3) void k_down(
    const short* __restrict__ act, const float* __restrict__ w2,
    const int* __restrict__ eoff, short* __restrict__ y) {
  __shared__ __align__(16) short a_s[2][128 * 32];  // 8 KB x2
  __shared__ __align__(16) short b_s[2][128 * 32];  // 8 KB x2

  int bxr = blockIdx.x;                       // 640 = 8 * 80 (XCD chunk)
  const int bx = (bxr & 7) * 80 + (bxr >> 3);
  const int tile = bx >> 4;
  const int nt = bx & 15;                     // 0..15 (128-wide h tile)
  const int row0 = tile * 128;
  if (row0 >= eoff[NEXP]) return;
  const int e = tile_expert(eoff, row0);

  const int tid = threadIdx.x;
  const int wid = tid >> 6;
  const int lane = tid & 63;
  const int wm = wid >> 1, wn = wid & 1;

  f32x4 acc[4][4] = {};

  const short* aG = act + (size_t)row0 * I_DIM;
  const float* bG = w2 + (size_t)e * H_DIM * I_DIM + (size_t)(nt * 128) * I_DIM;

  const int row  = tid >> 2;
  const int scol = ((tid & 3) ^ ((tid >> 3) & 3)) * 8;

  auto stageA = [&](int t, int bi) {   // 2 gload_lds
    const int ks = t * 32;
    load_lds16(aG + (size_t)row * I_DIM + ks + scol,        (char*)a_s[bi] + wid * 1024);
    load_lds16(aG + (size_t)(64 + row) * I_DIM + ks + scol, (char*)a_s[bi] + 4096 + wid * 1024);
  };
  auto ldB = [&](int t, f32x4& b00, f32x4& b01, f32x4& b10, f32x4& b11) {  // 4 loads
    const int ks = t * 32;
    const float* s0 = bG + (size_t)row * I_DIM + ks + scol;
    const float* s1 = bG + (size_t)(64 + row) * I_DIM + ks + scol;
    b00 = *(const f32x4*)s0; b01 = *(const f32x4*)(s0 + 4);
    b10 = *(const f32x4*)s1; b11 = *(const f32x4*)(s1 + 4);
  };
  auto wrB = [&](int bi, f32x4& b00, f32x4& b01, f32x4& b10, f32x4& b11) {
    *(short8*)((char*)b_s[bi] + tid * 16)        = cvt8(b00, b01);
    *(short8*)((char*)b_s[bi] + 4096 + tid * 16) = cvt8(b10, b11);
  };

  auto compute = [&](int bi) {
    const int asl = ((lane >> 4) ^ ((lane >> 1) & 3)) * 16;
    short8 af[4];
#pragma unroll
    for (int fm = 0; fm < 4; ++fm) {
      int m = wm * 64 + fm * 16 + (lane & 15);
      af[fm] = *(const short8*)((const char*)a_s[bi] + m * 64 + asl);
    }
#pragma unroll
    for (int fn = 0; fn < 4; ++fn) {
      int n = wn * 64 + fn * 16 + (lane & 15);
      short8 bb = *(const short8*)((const char*)b_s[bi] + n * 64 + asl);
#pragma unroll
      for (int fm = 0; fm < 4; ++fm)
        acc[fm][fn] = __builtin_amdgcn_mfma_f32_16x16x32_bf16(af[fm], bb, acc[fm][fn], 0, 0, 0);
    }
  };

  const int NK = I_DIM / 32;  // 44 (even)
  f32x4 e0, e1, e2, e3, o0, o1, o2, o3;

  stageA(0, 0);
  ldB(0, e0, e1, e2, e3);
  wrB(0, e0, e1, e2, e3);
  ldB(1, e0, e1, e2, e3);
  ldB(2, o0, o1, o2, o3);
  __syncthreads();

#define DN_STEP(T, B0, B1, B2, B3)                                            \
  {                                                                           \
    const int t_ = (T);                                                       \
    const int bi_ = t_ & 1;                                                   \
    const int tn_ = (t_ + 1 < NK) ? t_ + 1 : NK - 1;                          \
    const int tf_ = (t_ + 3 < NK) ? t_ + 3 : NK - 1;                          \
    stageA(tn_, bi_ ^ 1);                                                     \
    __builtin_amdgcn_sched_barrier(0);                                        \
    wrB(bi_ ^ 1, B0, B1, B2, B3);                                             \
    ldB(tf_, B0, B1, B2, B3);                                                 \
    compute(bi_);                                                             \
    asm volatile("s_waitcnt vmcnt(4) lgkmcnt(0)" ::: "memory");               \
    __builtin_amdgcn_s_barrier();                                             \
  }
  for (int tp = 0; tp < NK; tp += 2) {
    DN_STEP(tp,     e0, e1, e2, e3);
    DN_STEP(tp + 1, o0, o1, o2, o3);
  }
#undef DN_STEP
  asm volatile("s_waitcnt vmcnt(0)" ::: "memory");

#pragma unroll
  for (int fm = 0; fm < 4; ++fm) {
#pragma unroll
    for (int rr = 0; rr < 4; ++rr) {
      int m = wm * 64 + fm * 16 + (lane >> 4) * 4 + rr;
      size_t grow = (size_t)(row0 + m);
#pragma unroll
      for (int fn = 0; fn < 4; ++fn) {
        int col = nt * 128 + wn * 64 + fn * 16 + (lane & 15);
        y[grow * H_DIM + col] = f2bf(acc[fm][fn][rr]);
      }
    }
  }
}

// ---------------------------------------------------------------------------
// Kernel 5: combine: out[t] = w(p0)*y[p0] + w(p1)*y[p1]. bf16 y, f32 out.
// ---------------------------------------------------------------------------
__global__ void k_combine(const short* __restrict__ y,
                          const int* __restrict__ inv,
                          const float* __restrict__ pos_w,
                          float* __restrict__ out) {
  const int t = blockIdx.x;
  const int tid = threadIdx.x;
  const int p0 = inv[2 * t], p1 = inv[2 * t + 1];
  const float w0 = pos_w[p0], w1 = pos_w[p1];
  short8 a = ((const short8*)(y + (size_t)p0 * H_DIM))[tid];
  short8 b = ((const short8*)(y + (size_t)p1 * H_DIM))[tid];
  f32x4 r0, r1;
#pragma unroll
  for (int j = 0; j < 4; ++j) {
    r0[j] = w0 * bf2f(a[j]) + w1 * bf2f(b[j]);
    r1[j] = w0 * bf2f(a[j + 4]) + w1 * bf2f(b[j + 4]);
  }
  f32x4* o = (f32x4*)(out + (size_t)t * H_DIM);
  o[tid * 2]     = r0;
  o[tid * 2 + 1] = r1;
}

// ---------------------------------------------------------------------------
extern "C" void kernel_launch(void* const* d_in, const int* in_sizes, int n_in,
                              void* d_out, int out_size, void* d_ws, size_t ws_size,
                              hipStream_t stream) {
  const float* x      = (const float*)d_in[0];
  const float* logits = (const float*)d_in[1];
  const float* w13    = (const float*)d_in[2];
  const float* w2     = (const float*)d_in[3];
  (void)in_sizes; (void)n_in; (void)out_size; (void)ws_size;
  float* out = (float*)d_out;
  char* ws = (char*)d_ws;

  size_t o = 0;
  auto alloc = [&](size_t bytes) { size_t r = o; o += (bytes + 255) & ~(size_t)255; return r; };
  short* xg        = (short*)(ws + alloc((size_t)NPAD * H_DIM * 2));   // 21.0 MB
  short* act       = (short*)(ws + alloc((size_t)NPAD * I_DIM * 2));   // 14.4 MB
  short* y         = (short*)(ws + alloc((size_t)NPAD * H_DIM * 2));   // 21.0 MB
  int*   pos_token = (int*)  (ws + alloc((size_t)NPAD * 4));
  float* pos_w     = (float*)(ws + alloc((size_t)NPAD * 4));
  int*   inv       = (int*)  (ws + alloc((size_t)T_TOK * 2 * 4));
  int*   eoff      = (int*)  (ws + alloc((NEXP + 1) * 4));

  k_routing<<<1, 1024, 0, stream>>>(logits, pos_token, pos_w, eoff, inv);
  k_gather<<<NPAD, 256, 0, stream>>>(x, pos_token, xg);
  k_gateup<<<NEXP * 22 * 2, 256, 0, stream>>>(xg, w13, eoff, act);
  k_down<<<MAXT * 16, 256, 0, stream>>>(act, w2, eoff, y);
  k_combine<<<T_TOK, 256, 0, stream>>>(y, inv, pos_w, out);
}